// Round 10
// baseline (354.642 us; speedup 1.0000x reference)
//
#include <hip/hip_runtime.h>

#define N_NODES 50000
#define HIDDEN  128
#define N_EDGES 600000
#define BR      32                        // rows per tile in fused kernel
#define NB      ((N_NODES + 255) / 256)   // 196 scan blocks
#define NTILES  ((N_NODES + BR - 1) / BR) // 1563
#define E_PAD_MAX (N_EDGES + 3 * N_NODES) // 750000 max padded csr entries
#define SCSR_CAP 4096                     // staged csr entries per tile (8KB)

typedef __attribute__((ext_vector_type(8))) short short8v;
typedef __attribute__((ext_vector_type(4))) float f32x4;

// ---------------- threefry2x32 (JAX-exact, key = (0,42)) ----------------
__device__ __forceinline__ unsigned rotl32(unsigned v, int r) {
  return (v << r) | (v >> (32 - r));
}

__device__ __forceinline__ void threefry2x32(unsigned x0, unsigned x1,
                                             unsigned& o0, unsigned& o1) {
  const unsigned ks0 = 0u, ks1 = 42u;
  const unsigned ks2 = ks0 ^ ks1 ^ 0x1BD11BDAu;
  const unsigned ks[3] = {ks0, ks1, ks2};
  const int rot[2][4] = {{13, 15, 26, 6}, {17, 29, 16, 24}};
  x0 += ks0; x1 += ks1;
#pragma unroll
  for (int i = 0; i < 5; ++i) {
#pragma unroll
    for (int j = 0; j < 4; ++j) {
      x0 += x1;
      x1 = rotl32(x1, rot[i & 1][j]);
      x1 ^= x0;
    }
    x0 += ks[(i + 1) % 3];
    x1 += ks[(i + 2) % 3] + (unsigned)(i + 1);
  }
  o0 = x0; o1 = x1;
}

// JAX threefry_partitionable random_bits: bits[c] = o0^o1 of
// threefry(key=(0,42), counter=(0,c)); uniform = ((bits>>9)|0x3f800000)-1.
__device__ __forceinline__ float col_mask(int c) {
  unsigned o0, o1;
  threefry2x32(0u, (unsigned)c, o0, o1);
  unsigned bits = o0 ^ o1;
  float u = __uint_as_float((bits >> 9) | 0x3f800000u) - 1.0f;
  return (u < 0.75f) ? 1.0f : 0.0f;
}

__device__ __forceinline__ unsigned short f2bf(float f) {
  unsigned u = __float_as_uint(f);
  u += 0x7fffu + ((u >> 16) & 1u);  // round-to-nearest-even
  return (unsigned short)(u >> 16);
}

__device__ __forceinline__ float bflo(unsigned u) {
  return __uint_as_float(u << 16);
}
__device__ __forceinline__ float bfhi(unsigned u) {
  return __uint_as_float(u & 0xffff0000u);
}

__device__ __forceinline__ float rlane(float v, int l) {
  return __int_as_float(__builtin_amdgcn_readlane(__float_as_int(v), l));
}

// ---------------- prep: hist(dst) + xb = bf16(mask .* x) + Wt = bf16(W^T) --
__global__ __launch_bounds__(256) void prep_kernel(
    const float* __restrict__ x, const float* __restrict__ W1,
    const float* __restrict__ W2, const int* __restrict__ ei,
    unsigned short* __restrict__ xb, unsigned short* __restrict__ Wt1,
    unsigned short* __restrict__ Wt2, int* __restrict__ deg) {
  __shared__ float msk[HIDDEN];
  if (threadIdx.x < HIDDEN) msk[threadIdx.x] = col_mask(threadIdx.x);
  __syncthreads();

  const int gid = blockIdx.x * 256 + threadIdx.x;
  const int e0 = gid * 8;  // 8 contiguous elements
  if (e0 < N_NODES * HIDDEN) {
    const int c0 = e0 & (HIDDEN - 1);
    const float4 v0 = *reinterpret_cast<const float4*>(x + e0);
    const float4 v1 = *reinterpret_cast<const float4*>(x + e0 + 4);
    unsigned short h[8];
    h[0] = f2bf(v0.x * msk[c0 + 0]);
    h[1] = f2bf(v0.y * msk[c0 + 1]);
    h[2] = f2bf(v0.z * msk[c0 + 2]);
    h[3] = f2bf(v0.w * msk[c0 + 3]);
    h[4] = f2bf(v1.x * msk[c0 + 4]);
    h[5] = f2bf(v1.y * msk[c0 + 5]);
    h[6] = f2bf(v1.z * msk[c0 + 6]);
    h[7] = f2bf(v1.w * msk[c0 + 7]);
    *reinterpret_cast<uint4*>(xb + e0) = *reinterpret_cast<uint4*>(h);
  }
  if (gid < N_EDGES) atomicAdd(deg + ei[N_EDGES + gid], 1);
  if (gid < HIDDEN * HIDDEN / 4) {
#pragma unroll
    for (int i = 0; i < 4; ++i) {
      int t = gid * 4 + i;            // Wt index
      int col = t >> 7, k = t & 127;  // Wt[col][k] = W[k][col]
      Wt1[t] = f2bf(W1[k * HIDDEN + col]);
      Wt2[t] = f2bf(W2[k * HIDDEN + col]);
    }
  }
  if (gid < 16) {
    uint4 z; z.x = 0; z.y = 0; z.z = 0; z.w = 0;
    *reinterpret_cast<uint4*>(xb + (size_t)N_NODES * HIDDEN + gid * 8) = z;
  }
}

// ---------------- single-kernel chained scan (padded degrees) --------------
// 196 blocks, all co-resident (<< capacity) -> chained lookback is safe and
// deterministic. done[] zeroed by the launch-side memset.
__global__ __launch_bounds__(256) void scan_kernel(
    const int* __restrict__ deg, int* __restrict__ offs,
    int* __restrict__ pos, unsigned short* __restrict__ csr,
    int* __restrict__ pref, int* __restrict__ done) {
  __shared__ int s[256];
  __shared__ int sbase;
  const int t = threadIdx.x;
  const int b = blockIdx.x;
  const int idx = b * 256 + t;
  const int d = (idx < N_NODES) ? deg[idx] : 0;
  const int v = (d + 3) & ~3;
  s[t] = v;
  __syncthreads();
  int acc = v;
  for (int off = 1; off < 256; off <<= 1) {
    int add = (t >= off) ? s[t - off] : 0;
    __syncthreads();
    acc += add;
    s[t] = acc;
    __syncthreads();
  }
  if (t == 255) {
    int prev = 0;
    if (b > 0) {
      while (atomicAdd(&done[b - 1], 0) == 0) {
      }
      prev = atomicAdd(&pref[b - 1], 0);
    }
    pref[b] = prev + acc;
    __threadfence();
    atomicExch(&done[b], 1);
    sbase = prev;
    if (b == NB - 1) offs[N_NODES] = prev + acc;
  }
  __syncthreads();
  if (idx < N_NODES) {
    const int o = sbase + acc - v;
    offs[idx] = o;
    pos[idx] = o;
    for (int w = o + d; w < o + v; ++w)
      csr[w] = (unsigned short)N_NODES;  // pad -> zero row
  }
}

__global__ __launch_bounds__(256) void fill_kernel(const int* __restrict__ ei,
                                                   int* __restrict__ pos,
                                                   unsigned short* __restrict__ csr) {
  int e = blockIdx.x * blockDim.x + threadIdx.x;
  if (e >= N_EDGES) return;
  int src = ei[e];
  int dst = ei[N_EDGES + e];
  int p = atomicAdd(pos + dst, 1);
  csr[p] = (unsigned short)src;
}

// ---------------- gather: quarter-wave rows, depth-2 load pipeline ---------
// 16 lanes per row (uint4/16B -> 256B row); wave covers 4 rows per load
// instruction. Each iteration issues the NEXT 4 loads (branch-free: index
// select to the zero row when out of range) before accumulating the current
// 4 -> 2x loads in flight. Sum order per column identical to round 8/9.
template <bool LDSIDX>
__device__ __forceinline__ void gather2(
    int base, int wave, int q, int ql, int cs,
    const unsigned short* __restrict__ csr, const unsigned short* scsr,
    const int* loffs, const unsigned short* __restrict__ xb,
    unsigned short* H1) {
#pragma unroll 1
  for (int i = 0; i < 2; ++i) {
    const int row = wave * 8 + i * 4 + q;
    const int node = base + row;
    const bool valid = node < N_NODES;
    const int s = valid ? loffs[row] : 0;
    const int e = valid ? loffs[row + 1] : 0;
    const int on = valid ? node : N_NODES;  // invalid -> zero row
    const uint4 ov =
        *reinterpret_cast<const uint4*>(xb + (size_t)on * HIDDEN + ql * 8);
    float a0 = bflo(ov.x), a1 = bfhi(ov.x);
    float a2 = bflo(ov.y), a3 = bfhi(ov.y);
    float a4 = bflo(ov.z), a5 = bfhi(ov.z);
    float a6 = bflo(ov.w), a7 = bfhi(ov.w);

    // current indices/loads (zero row when empty)
    const bool h0 = s < e;
    uint2 pk;
    pk.x = 0; pk.y = 0;
    if (h0)
      pk = LDSIDX ? *reinterpret_cast<const uint2*>(scsr + (s - cs))
                  : *reinterpret_cast<const uint2*>(csr + s);
    int i0 = h0 ? (int)(pk.x & 0xffffu) : N_NODES;
    int i1 = h0 ? (int)(pk.x >> 16) : N_NODES;
    int i2 = h0 ? (int)(pk.y & 0xffffu) : N_NODES;
    int i3 = h0 ? (int)(pk.y >> 16) : N_NODES;
    uint4 c0 = *reinterpret_cast<const uint4*>(xb + (size_t)i0 * HIDDEN + ql * 8);
    uint4 c1 = *reinterpret_cast<const uint4*>(xb + (size_t)i1 * HIDDEN + ql * 8);
    uint4 c2 = *reinterpret_cast<const uint4*>(xb + (size_t)i2 * HIDDEN + ql * 8);
    uint4 c3 = *reinterpret_cast<const uint4*>(xb + (size_t)i3 * HIDDEN + ql * 8);

    for (int j = s; j < e; j += 4) {
      const int jn = j + 4;
      const bool more = jn < e;
      uint2 pk2;
      pk2.x = 0; pk2.y = 0;
      if (more)
        pk2 = LDSIDX ? *reinterpret_cast<const uint2*>(scsr + (jn - cs))
                     : *reinterpret_cast<const uint2*>(csr + jn);
      const int n0 = more ? (int)(pk2.x & 0xffffu) : N_NODES;
      const int n1 = more ? (int)(pk2.x >> 16) : N_NODES;
      const int n2 = more ? (int)(pk2.y & 0xffffu) : N_NODES;
      const int n3 = more ? (int)(pk2.y >> 16) : N_NODES;
      // issue next-iteration loads before consuming current
      const uint4 d0 =
          *reinterpret_cast<const uint4*>(xb + (size_t)n0 * HIDDEN + ql * 8);
      const uint4 d1 =
          *reinterpret_cast<const uint4*>(xb + (size_t)n1 * HIDDEN + ql * 8);
      const uint4 d2 =
          *reinterpret_cast<const uint4*>(xb + (size_t)n2 * HIDDEN + ql * 8);
      const uint4 d3 =
          *reinterpret_cast<const uint4*>(xb + (size_t)n3 * HIDDEN + ql * 8);

      a0 += bflo(c0.x) + bflo(c1.x) + bflo(c2.x) + bflo(c3.x);
      a1 += bfhi(c0.x) + bfhi(c1.x) + bfhi(c2.x) + bfhi(c3.x);
      a2 += bflo(c0.y) + bflo(c1.y) + bflo(c2.y) + bflo(c3.y);
      a3 += bfhi(c0.y) + bfhi(c1.y) + bfhi(c2.y) + bfhi(c3.y);
      a4 += bflo(c0.z) + bflo(c1.z) + bflo(c2.z) + bflo(c3.z);
      a5 += bfhi(c0.z) + bfhi(c1.z) + bfhi(c2.z) + bfhi(c3.z);
      a6 += bflo(c0.w) + bflo(c1.w) + bflo(c2.w) + bflo(c3.w);
      a7 += bfhi(c0.w) + bfhi(c1.w) + bfhi(c2.w) + bfhi(c3.w);

      c0 = d0; c1 = d1; c2 = d2; c3 = d3;
    }
    uint4 pw;
    pw.x = (unsigned)f2bf(a0) | ((unsigned)f2bf(a1) << 16);
    pw.y = (unsigned)f2bf(a2) | ((unsigned)f2bf(a3) << 16);
    pw.z = (unsigned)f2bf(a4) | ((unsigned)f2bf(a5) << 16);
    pw.w = (unsigned)f2bf(a6) | ((unsigned)f2bf(a7) << 16);
    const int byte = (row * 256 + ql * 16) ^ ((row & 7) << 4);
    *reinterpret_cast<uint4*>(reinterpret_cast<char*>(H1) + byte) = pw;
  }
}

// ---------------- fused gather(bf16) + MLP (bf16 MFMA) ----------------
__global__ __launch_bounds__(256) void fused_xb_kernel(
    const int* __restrict__ offs, const unsigned short* __restrict__ csr,
    const unsigned short* __restrict__ xb,
    const unsigned short* __restrict__ Wt1,
    const unsigned short* __restrict__ Wt2, const float* __restrict__ b1,
    const float* __restrict__ b2, float* __restrict__ out) {
  __shared__ unsigned short H1[BR * HIDDEN];              // 8 KB, swizzled
  __shared__ unsigned short H2[BR * HIDDEN];              // 8 KB, swizzled
  __shared__ __align__(16) unsigned short scsr[SCSR_CAP]; // 8 KB staged csr
  __shared__ int loffs[BR + 1];

  const int tid = threadIdx.x;
  const int lane = tid & 63;
  const int wave = tid >> 6;
  const int base = blockIdx.x * BR;

  if (tid < BR + 1) {
    int idx = base + tid;
    loffs[tid] = offs[idx > N_NODES ? N_NODES : idx];
  }
  __syncthreads();
  const int cs = loffs[0];
  const int count = loffs[BR] - cs;
  const bool stage = (count <= SCSR_CAP);
  if (stage) {
    const unsigned* src = reinterpret_cast<const unsigned*>(csr + cs);
    unsigned* dst = reinterpret_cast<unsigned*>(scsr);
    for (int k = tid; k < (count >> 1); k += 256) dst[k] = src[k];
  }
  __syncthreads();

  const int q = lane >> 4;   // quarter index: which row of the 4
  const int ql = lane & 15;  // lane in quarter: cols ql*8 .. ql*8+7

  if (stage)
    gather2<true>(base, wave, q, ql, cs, csr, scsr, loffs, xb, H1);
  else
    gather2<false>(base, wave, q, ql, cs, csr, scsr, loffs, xb, H1);
  __syncthreads();

  // ---- phase 2: GEMM1 (H1 @ Wt1 + b1, relu) -> H2 ----
  const int colbase = wave * 32;  // 2 col-tiles per wave
  float bias1[2], bias2[2];
#pragma unroll
  for (int c = 0; c < 2; ++c) {
    bias1[c] = b1[colbase + c * 16 + (lane & 15)];
    bias2[c] = b2[colbase + c * 16 + (lane & 15)];
  }

  f32x4 acc[2][2] = {};
#pragma unroll
  for (int kt = 0; kt < 4; ++kt) {
    short8v a[2], b[2];
#pragma unroll
    for (int r = 0; r < 2; ++r) {
      int row = r * 16 + (lane & 15);
      int byte = (row * 256 + kt * 64 + (lane >> 4) * 16) ^ ((row & 7) << 4);
      a[r] = *reinterpret_cast<const short8v*>(
          reinterpret_cast<const char*>(H1) + byte);
    }
#pragma unroll
    for (int c = 0; c < 2; ++c) {
      int col = colbase + c * 16 + (lane & 15);
      b[c] = *reinterpret_cast<const short8v*>(
          reinterpret_cast<const char*>(Wt1) + col * 256 + kt * 64 +
          (lane >> 4) * 16);
    }
#pragma unroll
    for (int r = 0; r < 2; ++r)
#pragma unroll
      for (int c = 0; c < 2; ++c)
        acc[r][c] = __builtin_amdgcn_mfma_f32_16x16x32_bf16(a[r], b[c],
                                                            acc[r][c], 0, 0, 0);
  }
#pragma unroll
  for (int r = 0; r < 2; ++r)
#pragma unroll
    for (int c = 0; c < 2; ++c)
#pragma unroll
      for (int q2 = 0; q2 < 4; ++q2) {
        int row = r * 16 + (lane >> 4) * 4 + q2;
        int col = colbase + c * 16 + (lane & 15);
        float v = fmaxf(acc[r][c][q2] + bias1[c], 0.f);
        int byte = (row * 256 + col * 2) ^ ((row & 7) << 4);
        *reinterpret_cast<unsigned short*>(reinterpret_cast<char*>(H2) + byte) =
            f2bf(v);
      }
  __syncthreads();

  // ---- phase 3: GEMM2 (H2 @ Wt2 + b2) -> out ----
  f32x4 acc2[2][2] = {};
#pragma unroll
  for (int kt = 0; kt < 4; ++kt) {
    short8v a[2], b[2];
#pragma unroll
    for (int r = 0; r < 2; ++r) {
      int row = r * 16 + (lane & 15);
      int byte = (row * 256 + kt * 64 + (lane >> 4) * 16) ^ ((row & 7) << 4);
      a[r] = *reinterpret_cast<const short8v*>(
          reinterpret_cast<const char*>(H2) + byte);
    }
#pragma unroll
    for (int c = 0; c < 2; ++c) {
      int col = colbase + c * 16 + (lane & 15);
      b[c] = *reinterpret_cast<const short8v*>(
          reinterpret_cast<const char*>(Wt2) + col * 256 + kt * 64 +
          (lane >> 4) * 16);
    }
#pragma unroll
    for (int r = 0; r < 2; ++r)
#pragma unroll
      for (int c = 0; c < 2; ++c)
        acc2[r][c] = __builtin_amdgcn_mfma_f32_16x16x32_bf16(
            a[r], b[c], acc2[r][c], 0, 0, 0);
  }
#pragma unroll
  for (int r = 0; r < 2; ++r)
#pragma unroll
    for (int c = 0; c < 2; ++c)
#pragma unroll
      for (int q2 = 0; q2 < 4; ++q2) {
        int row = base + r * 16 + (lane >> 4) * 4 + q2;
        if (row < N_NODES) {
          int col = colbase + c * 16 + (lane & 15);
          out[(size_t)row * HIDDEN + col] = acc2[r][c][q2] + bias2[c];
        }
      }
}

// ---------------- Tier-C fallback (round-2 proven) ----------------
__global__ __launch_bounds__(256) void scatter_kernel(
    const int* __restrict__ ei, const float* __restrict__ x,
    float* __restrict__ agg) {
  long long gid = (long long)blockIdx.x * blockDim.x + threadIdx.x;
  int e = (int)(gid >> 5);
  if (e >= N_EDGES) return;
  int sub = ((int)gid & 31) * 4;
  int src = ei[e];
  int dst = ei[N_EDGES + e];
  const float4 v = *reinterpret_cast<const float4*>(x + src * HIDDEN + sub);
  float* p = agg + dst * HIDDEN + sub;
  atomicAdd(p + 0, v.x);
  atomicAdd(p + 1, v.y);
  atomicAdd(p + 2, v.z);
  atomicAdd(p + 3, v.w);
}

__global__ __launch_bounds__(512) void mlp_kernel(
    const float* __restrict__ x, float* __restrict__ io,
    const float* __restrict__ W1, const float* __restrict__ b1,
    const float* __restrict__ W2, const float* __restrict__ b2) {
  __shared__ float W1s[HIDDEN * HIDDEN];
  __shared__ float W2s[HIDDEN * HIDDEN];

  const int tid = threadIdx.x;
#pragma unroll
  for (int i = 0; i < 8; ++i) {
    int idx = (i * 512 + tid) * 4;
    *reinterpret_cast<float4*>(W1s + idx) =
        *reinterpret_cast<const float4*>(W1 + idx);
    *reinterpret_cast<float4*>(W2s + idx) =
        *reinterpret_cast<const float4*>(W2 + idx);
  }

  const int lane = tid & 63;
  const int wave = tid >> 6;
  const int c0 = 2 * lane, c1 = 2 * lane + 1;

  const float m0 = col_mask(c0);
  const float m1 = col_mask(c1);
  const float bb1x = b1[c0], bb1y = b1[c1];
  const float bb2x = b2[c0], bb2y = b2[c1];

  __syncthreads();

  const int gwave = blockIdx.x * 8 + wave;
  const int nwaves = gridDim.x * 8;

  for (int pr = gwave; pr < N_NODES / 2; pr += nwaves) {
    const int baseA = (2 * pr) * HIDDEN;
    const int baseB = baseA + HIDDEN;

    float2 xA = *reinterpret_cast<const float2*>(x + baseA + c0);
    float2 gA = *reinterpret_cast<const float2*>(io + baseA + c0);
    float2 xB = *reinterpret_cast<const float2*>(x + baseB + c0);
    float2 gB = *reinterpret_cast<const float2*>(io + baseB + c0);

    float hA0 = m0 * (xA.x + gA.x), hA1 = m1 * (xA.y + gA.y);
    float hB0 = m0 * (xB.x + gB.x), hB1 = m1 * (xB.y + gB.y);

    float aA0 = bb1x, aA1 = bb1y, aB0 = bb1x, aB1 = bb1y;
#pragma unroll
    for (int k = 0; k < HIDDEN; ++k) {
      const int sl = k >> 1;
      float hkA = (k & 1) ? rlane(hA1, sl) : rlane(hA0, sl);
      float hkB = (k & 1) ? rlane(hB1, sl) : rlane(hB0, sl);
      float2 w = *reinterpret_cast<const float2*>(W1s + k * HIDDEN + c0);
      aA0 = fmaf(hkA, w.x, aA0);
      aA1 = fmaf(hkA, w.y, aA1);
      aB0 = fmaf(hkB, w.x, aB0);
      aB1 = fmaf(hkB, w.y, aB1);
    }
    aA0 = fmaxf(aA0, 0.0f); aA1 = fmaxf(aA1, 0.0f);
    aB0 = fmaxf(aB0, 0.0f); aB1 = fmaxf(aB1, 0.0f);

    float oA0 = bb2x, oA1 = bb2y, oB0 = bb2x, oB1 = bb2y;
#pragma unroll
    for (int k = 0; k < HIDDEN; ++k) {
      const int sl = k >> 1;
      float hkA = (k & 1) ? rlane(aA1, sl) : rlane(aA0, sl);
      float hkB = (k & 1) ? rlane(aB1, sl) : rlane(aB0, sl);
      float2 w = *reinterpret_cast<const float2*>(W2s + k * HIDDEN + c0);
      oA0 = fmaf(hkA, w.x, oA0);
      oA1 = fmaf(hkA, w.y, oA1);
      oB0 = fmaf(hkB, w.x, oB0);
      oB1 = fmaf(hkB, w.y, oB1);
    }

    *reinterpret_cast<float2*>(io + baseA + c0) = make_float2(oA0, oA1);
    *reinterpret_cast<float2*>(io + baseB + c0) = make_float2(oB0, oB1);
  }
}

extern "C" void kernel_launch(void* const* d_in, const int* in_sizes, int n_in,
                              void* d_out, int out_size, void* d_ws,
                              size_t ws_size, hipStream_t stream) {
  (void)in_sizes; (void)n_in; (void)out_size;
  const float* x  = (const float*)d_in[0];
  const int*   ei = (const int*)d_in[1];
  const float* W1 = (const float*)d_in[2];
  const float* b1 = (const float*)d_in[3];
  const float* W2 = (const float*)d_in[4];
  const float* b2 = (const float*)d_in[5];
  float* out = (float*)d_out;

  // ws layout: [ints: deg N | done NB | offs N+1 | pos N | pref NB] pad16
  //            [u16: csr E_PAD_MAX] [u16: Wt1 16384 | Wt2 16384]
  //            [u16: xb (N_NODES+1)*HIDDEN]
  // memset zeroes deg+done (contiguous).
  const size_t int_words = (size_t)N_NODES + NB + (N_NODES + 1) + N_NODES + NB;
  const size_t int_pad   = (int_words * 4 + 15) & ~(size_t)15;
  const size_t csr_bytes = (size_t)E_PAD_MAX * 2;
  const size_t wt_bytes  = 2 * (size_t)HIDDEN * HIDDEN * 2;
  const size_t xb_bytes  = (size_t)(N_NODES + 1) * HIDDEN * 2;
  const size_t need = int_pad + csr_bytes + wt_bytes + xb_bytes;

  if (ws_size >= need) {
    char* wsb = (char*)d_ws;
    int* deg  = (int*)wsb;
    int* done = deg + N_NODES;
    int* offs = done + NB;
    int* pos  = offs + N_NODES + 1;
    int* pref = pos + N_NODES;
    unsigned short* csr = (unsigned short*)(wsb + int_pad);
    unsigned short* Wt1 = (unsigned short*)(wsb + int_pad + csr_bytes);
    unsigned short* Wt2 = Wt1 + HIDDEN * HIDDEN;
    unsigned short* xb  = Wt2 + HIDDEN * HIDDEN;

    hipMemsetAsync(deg, 0, (size_t)(N_NODES + NB) * 4, stream);
    const int nprep = (N_NODES * HIDDEN / 8 + 255) / 256;  // 3125
    prep_kernel<<<nprep, 256, 0, stream>>>(x, W1, W2, ei, xb, Wt1, Wt2, deg);
    scan_kernel<<<NB, 256, 0, stream>>>(deg, offs, pos, csr, pref, done);
    fill_kernel<<<(N_EDGES + 255) / 256, 256, 0, stream>>>(ei, pos, csr);
    fused_xb_kernel<<<NTILES, 256, 0, stream>>>(offs, csr, xb, Wt1, Wt2, b1,
                                                b2, out);
  } else {
    // Tier C: atomic scatter + rlane MLP (proven, slow).
    hipMemsetAsync(out, 0, (size_t)N_NODES * HIDDEN * sizeof(float), stream);
    const long long total = (long long)N_EDGES * 32;
    scatter_kernel<<<(int)((total + 255) / 256), 256, 0, stream>>>(ei, x, out);
    mlp_kernel<<<256, 512, 0, stream>>>(x, out, W1, b1, W2, b2);
  }
}

// Round 11
// 117.673 us; speedup vs baseline: 3.0138x; 3.0138x over previous
//
#include <hip/hip_runtime.h>

#define N_NODES 50000
#define HIDDEN  128
#define N_EDGES 600000
#define BR      32                        // rows per tile in fused kernel
#define NB      ((N_NODES + 255) / 256)   // 196 scan blocks
#define NTILES  ((N_NODES + BR - 1) / BR) // 1563
#define E_PAD_MAX (N_EDGES + 3 * N_NODES) // 750000 max padded csr entries
#define SCSR_CAP 4096                     // staged csr entries per tile (8KB)

typedef __attribute__((ext_vector_type(8))) short short8v;
typedef __attribute__((ext_vector_type(4))) float f32x4;

// ---------------- threefry2x32 (JAX-exact, key = (0,42)) ----------------
__device__ __forceinline__ unsigned rotl32(unsigned v, int r) {
  return (v << r) | (v >> (32 - r));
}

__device__ __forceinline__ void threefry2x32(unsigned x0, unsigned x1,
                                             unsigned& o0, unsigned& o1) {
  const unsigned ks0 = 0u, ks1 = 42u;
  const unsigned ks2 = ks0 ^ ks1 ^ 0x1BD11BDAu;
  const unsigned ks[3] = {ks0, ks1, ks2};
  const int rot[2][4] = {{13, 15, 26, 6}, {17, 29, 16, 24}};
  x0 += ks0; x1 += ks1;
#pragma unroll
  for (int i = 0; i < 5; ++i) {
#pragma unroll
    for (int j = 0; j < 4; ++j) {
      x0 += x1;
      x1 = rotl32(x1, rot[i & 1][j]);
      x1 ^= x0;
    }
    x0 += ks[(i + 1) % 3];
    x1 += ks[(i + 2) % 3] + (unsigned)(i + 1);
  }
  o0 = x0; o1 = x1;
}

// JAX threefry_partitionable random_bits: bits[c] = o0^o1 of
// threefry(key=(0,42), counter=(0,c)); uniform = ((bits>>9)|0x3f800000)-1.
__device__ __forceinline__ float col_mask(int c) {
  unsigned o0, o1;
  threefry2x32(0u, (unsigned)c, o0, o1);
  unsigned bits = o0 ^ o1;
  float u = __uint_as_float((bits >> 9) | 0x3f800000u) - 1.0f;
  return (u < 0.75f) ? 1.0f : 0.0f;
}

__device__ __forceinline__ unsigned short f2bf(float f) {
  unsigned u = __float_as_uint(f);
  u += 0x7fffu + ((u >> 16) & 1u);  // round-to-nearest-even
  return (unsigned short)(u >> 16);
}

__device__ __forceinline__ float bflo(unsigned u) {
  return __uint_as_float(u << 16);
}
__device__ __forceinline__ float bfhi(unsigned u) {
  return __uint_as_float(u & 0xffff0000u);
}

__device__ __forceinline__ float rlane(float v, int l) {
  return __int_as_float(__builtin_amdgcn_readlane(__float_as_int(v), l));
}

// ---------------- prep: hist(dst) + xb = bf16(mask .* x) + Wt = bf16(W^T) --
__global__ __launch_bounds__(256) void prep_kernel(
    const float* __restrict__ x, const float* __restrict__ W1,
    const float* __restrict__ W2, const int* __restrict__ ei,
    unsigned short* __restrict__ xb, unsigned short* __restrict__ Wt1,
    unsigned short* __restrict__ Wt2, int* __restrict__ deg) {
  __shared__ float msk[HIDDEN];
  if (threadIdx.x < HIDDEN) msk[threadIdx.x] = col_mask(threadIdx.x);
  __syncthreads();

  const int gid = blockIdx.x * 256 + threadIdx.x;
  const int e0 = gid * 8;  // 8 contiguous elements
  if (e0 < N_NODES * HIDDEN) {
    const int c0 = e0 & (HIDDEN - 1);
    const float4 v0 = *reinterpret_cast<const float4*>(x + e0);
    const float4 v1 = *reinterpret_cast<const float4*>(x + e0 + 4);
    unsigned short h[8];
    h[0] = f2bf(v0.x * msk[c0 + 0]);
    h[1] = f2bf(v0.y * msk[c0 + 1]);
    h[2] = f2bf(v0.z * msk[c0 + 2]);
    h[3] = f2bf(v0.w * msk[c0 + 3]);
    h[4] = f2bf(v1.x * msk[c0 + 4]);
    h[5] = f2bf(v1.y * msk[c0 + 5]);
    h[6] = f2bf(v1.z * msk[c0 + 6]);
    h[7] = f2bf(v1.w * msk[c0 + 7]);
    *reinterpret_cast<uint4*>(xb + e0) = *reinterpret_cast<uint4*>(h);
  }
  if (gid < N_EDGES) atomicAdd(deg + ei[N_EDGES + gid], 1);
  if (gid < HIDDEN * HIDDEN / 4) {
#pragma unroll
    for (int i = 0; i < 4; ++i) {
      int t = gid * 4 + i;            // Wt index
      int col = t >> 7, k = t & 127;  // Wt[col][k] = W[k][col]
      Wt1[t] = f2bf(W1[k * HIDDEN + col]);
      Wt2[t] = f2bf(W2[k * HIDDEN + col]);
    }
  }
  if (gid < 16) {
    uint4 z; z.x = 0; z.y = 0; z.z = 0; z.w = 0;
    *reinterpret_cast<uint4*>(xb + (size_t)N_NODES * HIDDEN + gid * 8) = z;
  }
}

// ---------------- two-level scan over PADDED degrees (r8/r9 proven) --------
__global__ __launch_bounds__(256) void scanA_kernel(const int* __restrict__ deg,
                                                    int* __restrict__ bsum) {
  int idx = blockIdx.x * 256 + threadIdx.x;
  int v = (idx < N_NODES) ? ((deg[idx] + 3) & ~3) : 0;
#pragma unroll
  for (int off = 32; off; off >>= 1) v += __shfl_down(v, off, 64);
  __shared__ int ws4[4];
  if ((threadIdx.x & 63) == 0) ws4[threadIdx.x >> 6] = v;
  __syncthreads();
  if (threadIdx.x == 0) bsum[blockIdx.x] = ws4[0] + ws4[1] + ws4[2] + ws4[3];
}

__global__ __launch_bounds__(256) void scanB_kernel(const int* __restrict__ bsum,
                                                    int* __restrict__ bpre,
                                                    int* __restrict__ offs) {
  __shared__ int s[256];
  const int t = threadIdx.x;
  int v = (t < NB) ? bsum[t] : 0;
  s[t] = v;
  __syncthreads();
  int acc = v;
  for (int off = 1; off < 256; off <<= 1) {
    int add = (t >= off) ? s[t - off] : 0;
    __syncthreads();
    acc += add;
    s[t] = acc;
    __syncthreads();
  }
  if (t < NB) bpre[t] = acc - v;              // exclusive prefix
  if (t == 0) offs[N_NODES] = s[255];         // total padded edge count
}

// Stage C: local scan of padded degrees + write pad slots (dummy node).
__global__ __launch_bounds__(256) void scanC_kernel(
    const int* __restrict__ deg, const int* __restrict__ bpre,
    int* __restrict__ offs, int* __restrict__ pos,
    unsigned short* __restrict__ csr) {
  __shared__ int s[256];
  const int t = threadIdx.x;
  const int idx = blockIdx.x * 256 + t;
  int d = (idx < N_NODES) ? deg[idx] : 0;
  int v = (d + 3) & ~3;
  s[t] = v;
  __syncthreads();
  int acc = v;
  for (int off = 1; off < 256; off <<= 1) {
    int add = (t >= off) ? s[t - off] : 0;
    __syncthreads();
    acc += add;
    s[t] = acc;
    __syncthreads();
  }
  if (idx < N_NODES) {
    int o = bpre[blockIdx.x] + acc - v;
    offs[idx] = o;
    pos[idx] = o;
    for (int w = o + d; w < o + v; ++w)
      csr[w] = (unsigned short)N_NODES;  // pad -> zero row
  }
}

__global__ __launch_bounds__(256) void fill_kernel(const int* __restrict__ ei,
                                                   int* __restrict__ pos,
                                                   unsigned short* __restrict__ csr) {
  int e = blockIdx.x * blockDim.x + threadIdx.x;
  if (e >= N_EDGES) return;
  int src = ei[e];
  int dst = ei[N_EDGES + e];
  int p = atomicAdd(pos + dst, 1);
  csr[p] = (unsigned short)src;
}

// ---------------- gather: quarter-wave rows, depth-2 load pipeline ---------
// 16 lanes per row (uint4/16B -> 256B row); wave covers 4 rows per load
// instruction. Each iteration issues the NEXT 4 loads (branch-free: index
// select to the zero row when out of range) before accumulating the current
// 4 -> 2x loads in flight. Sum order per column identical to round 8/9.
template <bool LDSIDX>
__device__ __forceinline__ void gather2(
    int base, int wave, int q, int ql, int cs,
    const unsigned short* __restrict__ csr, const unsigned short* scsr,
    const int* loffs, const unsigned short* __restrict__ xb,
    unsigned short* H1) {
#pragma unroll 1
  for (int i = 0; i < 2; ++i) {
    const int row = wave * 8 + i * 4 + q;
    const int node = base + row;
    const bool valid = node < N_NODES;
    const int s = valid ? loffs[row] : 0;
    const int e = valid ? loffs[row + 1] : 0;
    const int on = valid ? node : N_NODES;  // invalid -> zero row
    const uint4 ov =
        *reinterpret_cast<const uint4*>(xb + (size_t)on * HIDDEN + ql * 8);
    float a0 = bflo(ov.x), a1 = bfhi(ov.x);
    float a2 = bflo(ov.y), a3 = bfhi(ov.y);
    float a4 = bflo(ov.z), a5 = bfhi(ov.z);
    float a6 = bflo(ov.w), a7 = bfhi(ov.w);

    // current indices/loads (zero row when empty)
    const bool h0 = s < e;
    uint2 pk;
    pk.x = 0; pk.y = 0;
    if (h0)
      pk = LDSIDX ? *reinterpret_cast<const uint2*>(scsr + (s - cs))
                  : *reinterpret_cast<const uint2*>(csr + s);
    int i0 = h0 ? (int)(pk.x & 0xffffu) : N_NODES;
    int i1 = h0 ? (int)(pk.x >> 16) : N_NODES;
    int i2 = h0 ? (int)(pk.y & 0xffffu) : N_NODES;
    int i3 = h0 ? (int)(pk.y >> 16) : N_NODES;
    uint4 c0 = *reinterpret_cast<const uint4*>(xb + (size_t)i0 * HIDDEN + ql * 8);
    uint4 c1 = *reinterpret_cast<const uint4*>(xb + (size_t)i1 * HIDDEN + ql * 8);
    uint4 c2 = *reinterpret_cast<const uint4*>(xb + (size_t)i2 * HIDDEN + ql * 8);
    uint4 c3 = *reinterpret_cast<const uint4*>(xb + (size_t)i3 * HIDDEN + ql * 8);

    for (int j = s; j < e; j += 4) {
      const int jn = j + 4;
      const bool more = jn < e;
      uint2 pk2;
      pk2.x = 0; pk2.y = 0;
      if (more)
        pk2 = LDSIDX ? *reinterpret_cast<const uint2*>(scsr + (jn - cs))
                     : *reinterpret_cast<const uint2*>(csr + jn);
      const int n0 = more ? (int)(pk2.x & 0xffffu) : N_NODES;
      const int n1 = more ? (int)(pk2.x >> 16) : N_NODES;
      const int n2 = more ? (int)(pk2.y & 0xffffu) : N_NODES;
      const int n3 = more ? (int)(pk2.y >> 16) : N_NODES;
      // issue next-iteration loads before consuming current
      const uint4 d0 =
          *reinterpret_cast<const uint4*>(xb + (size_t)n0 * HIDDEN + ql * 8);
      const uint4 d1 =
          *reinterpret_cast<const uint4*>(xb + (size_t)n1 * HIDDEN + ql * 8);
      const uint4 d2 =
          *reinterpret_cast<const uint4*>(xb + (size_t)n2 * HIDDEN + ql * 8);
      const uint4 d3 =
          *reinterpret_cast<const uint4*>(xb + (size_t)n3 * HIDDEN + ql * 8);

      a0 += bflo(c0.x) + bflo(c1.x) + bflo(c2.x) + bflo(c3.x);
      a1 += bfhi(c0.x) + bfhi(c1.x) + bfhi(c2.x) + bfhi(c3.x);
      a2 += bflo(c0.y) + bflo(c1.y) + bflo(c2.y) + bflo(c3.y);
      a3 += bfhi(c0.y) + bfhi(c1.y) + bfhi(c2.y) + bfhi(c3.y);
      a4 += bflo(c0.z) + bflo(c1.z) + bflo(c2.z) + bflo(c3.z);
      a5 += bfhi(c0.z) + bfhi(c1.z) + bfhi(c2.z) + bfhi(c3.z);
      a6 += bflo(c0.w) + bflo(c1.w) + bflo(c2.w) + bflo(c3.w);
      a7 += bfhi(c0.w) + bfhi(c1.w) + bfhi(c2.w) + bfhi(c3.w);

      c0 = d0; c1 = d1; c2 = d2; c3 = d3;
    }
    uint4 pw;
    pw.x = (unsigned)f2bf(a0) | ((unsigned)f2bf(a1) << 16);
    pw.y = (unsigned)f2bf(a2) | ((unsigned)f2bf(a3) << 16);
    pw.z = (unsigned)f2bf(a4) | ((unsigned)f2bf(a5) << 16);
    pw.w = (unsigned)f2bf(a6) | ((unsigned)f2bf(a7) << 16);
    const int byte = (row * 256 + ql * 16) ^ ((row & 7) << 4);
    *reinterpret_cast<uint4*>(reinterpret_cast<char*>(H1) + byte) = pw;
  }
}

// ---------------- fused gather(bf16) + MLP (bf16 MFMA) ----------------
__global__ __launch_bounds__(256) void fused_xb_kernel(
    const int* __restrict__ offs, const unsigned short* __restrict__ csr,
    const unsigned short* __restrict__ xb,
    const unsigned short* __restrict__ Wt1,
    const unsigned short* __restrict__ Wt2, const float* __restrict__ b1,
    const float* __restrict__ b2, float* __restrict__ out) {
  __shared__ unsigned short H1[BR * HIDDEN];              // 8 KB, swizzled
  __shared__ unsigned short H2[BR * HIDDEN];              // 8 KB, swizzled
  __shared__ __align__(16) unsigned short scsr[SCSR_CAP]; // 8 KB staged csr
  __shared__ int loffs[BR + 1];

  const int tid = threadIdx.x;
  const int lane = tid & 63;
  const int wave = tid >> 6;
  const int base = blockIdx.x * BR;

  if (tid < BR + 1) {
    int idx = base + tid;
    loffs[tid] = offs[idx > N_NODES ? N_NODES : idx];
  }
  __syncthreads();
  const int cs = loffs[0];
  const int count = loffs[BR] - cs;
  const bool stage = (count <= SCSR_CAP);
  if (stage) {
    const unsigned* src = reinterpret_cast<const unsigned*>(csr + cs);
    unsigned* dst = reinterpret_cast<unsigned*>(scsr);
    for (int k = tid; k < (count >> 1); k += 256) dst[k] = src[k];
  }
  __syncthreads();

  const int q = lane >> 4;   // quarter index: which row of the 4
  const int ql = lane & 15;  // lane in quarter: cols ql*8 .. ql*8+7

  if (stage)
    gather2<true>(base, wave, q, ql, cs, csr, scsr, loffs, xb, H1);
  else
    gather2<false>(base, wave, q, ql, cs, csr, scsr, loffs, xb, H1);
  __syncthreads();

  // ---- phase 2: GEMM1 (H1 @ Wt1 + b1, relu) -> H2 ----
  const int colbase = wave * 32;  // 2 col-tiles per wave
  float bias1[2], bias2[2];
#pragma unroll
  for (int c = 0; c < 2; ++c) {
    bias1[c] = b1[colbase + c * 16 + (lane & 15)];
    bias2[c] = b2[colbase + c * 16 + (lane & 15)];
  }

  f32x4 acc[2][2] = {};
#pragma unroll
  for (int kt = 0; kt < 4; ++kt) {
    short8v a[2], b[2];
#pragma unroll
    for (int r = 0; r < 2; ++r) {
      int row = r * 16 + (lane & 15);
      int byte = (row * 256 + kt * 64 + (lane >> 4) * 16) ^ ((row & 7) << 4);
      a[r] = *reinterpret_cast<const short8v*>(
          reinterpret_cast<const char*>(H1) + byte);
    }
#pragma unroll
    for (int c = 0; c < 2; ++c) {
      int col = colbase + c * 16 + (lane & 15);
      b[c] = *reinterpret_cast<const short8v*>(
          reinterpret_cast<const char*>(Wt1) + col * 256 + kt * 64 +
          (lane >> 4) * 16);
    }
#pragma unroll
    for (int r = 0; r < 2; ++r)
#pragma unroll
      for (int c = 0; c < 2; ++c)
        acc[r][c] = __builtin_amdgcn_mfma_f32_16x16x32_bf16(a[r], b[c],
                                                            acc[r][c], 0, 0, 0);
  }
#pragma unroll
  for (int r = 0; r < 2; ++r)
#pragma unroll
    for (int c = 0; c < 2; ++c)
#pragma unroll
      for (int q2 = 0; q2 < 4; ++q2) {
        int row = r * 16 + (lane >> 4) * 4 + q2;
        int col = colbase + c * 16 + (lane & 15);
        float v = fmaxf(acc[r][c][q2] + bias1[c], 0.f);
        int byte = (row * 256 + col * 2) ^ ((row & 7) << 4);
        *reinterpret_cast<unsigned short*>(reinterpret_cast<char*>(H2) + byte) =
            f2bf(v);
      }
  __syncthreads();

  // ---- phase 3: GEMM2 (H2 @ Wt2 + b2) -> out ----
  f32x4 acc2[2][2] = {};
#pragma unroll
  for (int kt = 0; kt < 4; ++kt) {
    short8v a[2], b[2];
#pragma unroll
    for (int r = 0; r < 2; ++r) {
      int row = r * 16 + (lane & 15);
      int byte = (row * 256 + kt * 64 + (lane >> 4) * 16) ^ ((row & 7) << 4);
      a[r] = *reinterpret_cast<const short8v*>(
          reinterpret_cast<const char*>(H2) + byte);
    }
#pragma unroll
    for (int c = 0; c < 2; ++c) {
      int col = colbase + c * 16 + (lane & 15);
      b[c] = *reinterpret_cast<const short8v*>(
          reinterpret_cast<const char*>(Wt2) + col * 256 + kt * 64 +
          (lane >> 4) * 16);
    }
#pragma unroll
    for (int r = 0; r < 2; ++r)
#pragma unroll
      for (int c = 0; c < 2; ++c)
        acc2[r][c] = __builtin_amdgcn_mfma_f32_16x16x32_bf16(
            a[r], b[c], acc2[r][c], 0, 0, 0);
  }
#pragma unroll
  for (int r = 0; r < 2; ++r)
#pragma unroll
    for (int c = 0; c < 2; ++c)
#pragma unroll
      for (int q2 = 0; q2 < 4; ++q2) {
        int row = base + r * 16 + (lane >> 4) * 4 + q2;
        if (row < N_NODES) {
          int col = colbase + c * 16 + (lane & 15);
          out[(size_t)row * HIDDEN + col] = acc2[r][c][q2] + bias2[c];
        }
      }
}

// ---------------- Tier-C fallback (round-2 proven) ----------------
__global__ __launch_bounds__(256) void scatter_kernel(
    const int* __restrict__ ei, const float* __restrict__ x,
    float* __restrict__ agg) {
  long long gid = (long long)blockIdx.x * blockDim.x + threadIdx.x;
  int e = (int)(gid >> 5);
  if (e >= N_EDGES) return;
  int sub = ((int)gid & 31) * 4;
  int src = ei[e];
  int dst = ei[N_EDGES + e];
  const float4 v = *reinterpret_cast<const float4*>(x + src * HIDDEN + sub);
  float* p = agg + dst * HIDDEN + sub;
  atomicAdd(p + 0, v.x);
  atomicAdd(p + 1, v.y);
  atomicAdd(p + 2, v.z);
  atomicAdd(p + 3, v.w);
}

__global__ __launch_bounds__(512) void mlp_kernel(
    const float* __restrict__ x, float* __restrict__ io,
    const float* __restrict__ W1, const float* __restrict__ b1,
    const float* __restrict__ W2, const float* __restrict__ b2) {
  __shared__ float W1s[HIDDEN * HIDDEN];
  __shared__ float W2s[HIDDEN * HIDDEN];

  const int tid = threadIdx.x;
#pragma unroll
  for (int i = 0; i < 8; ++i) {
    int idx = (i * 512 + tid) * 4;
    *reinterpret_cast<float4*>(W1s + idx) =
        *reinterpret_cast<const float4*>(W1 + idx);
    *reinterpret_cast<float4*>(W2s + idx) =
        *reinterpret_cast<const float4*>(W2 + idx);
  }

  const int lane = tid & 63;
  const int wave = tid >> 6;
  const int c0 = 2 * lane, c1 = 2 * lane + 1;

  const float m0 = col_mask(c0);
  const float m1 = col_mask(c1);
  const float bb1x = b1[c0], bb1y = b1[c1];
  const float bb2x = b2[c0], bb2y = b2[c1];

  __syncthreads();

  const int gwave = blockIdx.x * 8 + wave;
  const int nwaves = gridDim.x * 8;

  for (int pr = gwave; pr < N_NODES / 2; pr += nwaves) {
    const int baseA = (2 * pr) * HIDDEN;
    const int baseB = baseA + HIDDEN;

    float2 xA = *reinterpret_cast<const float2*>(x + baseA + c0);
    float2 gA = *reinterpret_cast<const float2*>(io + baseA + c0);
    float2 xB = *reinterpret_cast<const float2*>(x + baseB + c0);
    float2 gB = *reinterpret_cast<const float2*>(io + baseB + c0);

    float hA0 = m0 * (xA.x + gA.x), hA1 = m1 * (xA.y + gA.y);
    float hB0 = m0 * (xB.x + gB.x), hB1 = m1 * (xB.y + gB.y);

    float aA0 = bb1x, aA1 = bb1y, aB0 = bb1x, aB1 = bb1y;
#pragma unroll
    for (int k = 0; k < HIDDEN; ++k) {
      const int sl = k >> 1;
      float hkA = (k & 1) ? rlane(hA1, sl) : rlane(hA0, sl);
      float hkB = (k & 1) ? rlane(hB1, sl) : rlane(hB0, sl);
      float2 w = *reinterpret_cast<const float2*>(W1s + k * HIDDEN + c0);
      aA0 = fmaf(hkA, w.x, aA0);
      aA1 = fmaf(hkA, w.y, aA1);
      aB0 = fmaf(hkB, w.x, aB0);
      aB1 = fmaf(hkB, w.y, aB1);
    }
    aA0 = fmaxf(aA0, 0.0f); aA1 = fmaxf(aA1, 0.0f);
    aB0 = fmaxf(aB0, 0.0f); aB1 = fmaxf(aB1, 0.0f);

    float oA0 = bb2x, oA1 = bb2y, oB0 = bb2x, oB1 = bb2y;
#pragma unroll
    for (int k = 0; k < HIDDEN; ++k) {
      const int sl = k >> 1;
      float hkA = (k & 1) ? rlane(aA1, sl) : rlane(aA0, sl);
      float hkB = (k & 1) ? rlane(aB1, sl) : rlane(aB0, sl);
      float2 w = *reinterpret_cast<const float2*>(W2s + k * HIDDEN + c0);
      oA0 = fmaf(hkA, w.x, oA0);
      oA1 = fmaf(hkA, w.y, oA1);
      oB0 = fmaf(hkB, w.x, oB0);
      oB1 = fmaf(hkB, w.y, oB1);
    }

    *reinterpret_cast<float2*>(io + baseA + c0) = make_float2(oA0, oA1);
    *reinterpret_cast<float2*>(io + baseB + c0) = make_float2(oB0, oB1);
  }
}

extern "C" void kernel_launch(void* const* d_in, const int* in_sizes, int n_in,
                              void* d_out, int out_size, void* d_ws,
                              size_t ws_size, hipStream_t stream) {
  (void)in_sizes; (void)n_in; (void)out_size;
  const float* x  = (const float*)d_in[0];
  const int*   ei = (const int*)d_in[1];
  const float* W1 = (const float*)d_in[2];
  const float* b1 = (const float*)d_in[3];
  const float* W2 = (const float*)d_in[4];
  const float* b2 = (const float*)d_in[5];
  float* out = (float*)d_out;

  // ws layout: [ints: deg N | offs N+1 | pos N | bsum NB | bpre NB] pad16
  //            [u16: csr E_PAD_MAX] [u16: Wt1 16384 | Wt2 16384]
  //            [u16: xb (N_NODES+1)*HIDDEN]
  const size_t int_words = (size_t)N_NODES + (N_NODES + 1) + N_NODES + 2 * NB;
  const size_t int_pad   = (int_words * 4 + 15) & ~(size_t)15;
  const size_t csr_bytes = (size_t)E_PAD_MAX * 2;
  const size_t wt_bytes  = 2 * (size_t)HIDDEN * HIDDEN * 2;
  const size_t xb_bytes  = (size_t)(N_NODES + 1) * HIDDEN * 2;
  const size_t need = int_pad + csr_bytes + wt_bytes + xb_bytes;

  if (ws_size >= need) {
    char* wsb = (char*)d_ws;
    int* deg  = (int*)wsb;
    int* offs = deg + N_NODES;
    int* pos  = offs + N_NODES + 1;
    int* bsum = pos + N_NODES;
    int* bpre = bsum + NB;
    unsigned short* csr = (unsigned short*)(wsb + int_pad);
    unsigned short* Wt1 = (unsigned short*)(wsb + int_pad + csr_bytes);
    unsigned short* Wt2 = Wt1 + HIDDEN * HIDDEN;
    unsigned short* xb  = Wt2 + HIDDEN * HIDDEN;

    hipMemsetAsync(deg, 0, (size_t)N_NODES * 4, stream);
    const int nprep = (N_NODES * HIDDEN / 8 + 255) / 256;  // 3125
    prep_kernel<<<nprep, 256, 0, stream>>>(x, W1, W2, ei, xb, Wt1, Wt2, deg);
    scanA_kernel<<<NB, 256, 0, stream>>>(deg, bsum);
    scanB_kernel<<<1, 256, 0, stream>>>(bsum, bpre, offs);
    scanC_kernel<<<NB, 256, 0, stream>>>(deg, bpre, offs, pos, csr);
    fill_kernel<<<(N_EDGES + 255) / 256, 256, 0, stream>>>(ei, pos, csr);
    fused_xb_kernel<<<NTILES, 256, 0, stream>>>(offs, csr, xb, Wt1, Wt2, b1,
                                                b2, out);
  } else {
    // Tier C: atomic scatter + rlane MLP (proven, slow).
    hipMemsetAsync(out, 0, (size_t)N_NODES * HIDDEN * sizeof(float), stream);
    const long long total = (long long)N_EDGES * 32;
    scatter_kernel<<<(int)((total + 255) / 256), 256, 0, stream>>>(ei, x, out);
    mlp_kernel<<<256, 512, 0, stream>>>(x, out, W1, b1, W2, b2);
  }
}

// Round 12
// 116.919 us; speedup vs baseline: 3.0332x; 1.0065x over previous
//
#include <hip/hip_runtime.h>

#define N_NODES 50000
#define HIDDEN  128
#define N_EDGES 600000
#define BR      32                        // rows per tile in fused kernel
#define NB      ((N_NODES + 255) / 256)   // 196 scan blocks
#define NTILES  ((N_NODES + BR - 1) / BR) // 1563
#define E_PAD_MAX (N_EDGES + 3 * N_NODES) // 750000 max padded csr entries
#define SCSR_CAP 4096                     // staged csr entries per tile (8KB)

typedef __attribute__((ext_vector_type(8))) short short8v;
typedef __attribute__((ext_vector_type(4))) float f32x4;

// ---------------- threefry2x32 (JAX-exact, key = (0,42)) ----------------
__device__ __forceinline__ unsigned rotl32(unsigned v, int r) {
  return (v << r) | (v >> (32 - r));
}

__device__ __forceinline__ void threefry2x32(unsigned x0, unsigned x1,
                                             unsigned& o0, unsigned& o1) {
  const unsigned ks0 = 0u, ks1 = 42u;
  const unsigned ks2 = ks0 ^ ks1 ^ 0x1BD11BDAu;
  const unsigned ks[3] = {ks0, ks1, ks2};
  const int rot[2][4] = {{13, 15, 26, 6}, {17, 29, 16, 24}};
  x0 += ks0; x1 += ks1;
#pragma unroll
  for (int i = 0; i < 5; ++i) {
#pragma unroll
    for (int j = 0; j < 4; ++j) {
      x0 += x1;
      x1 = rotl32(x1, rot[i & 1][j]);
      x1 ^= x0;
    }
    x0 += ks[(i + 1) % 3];
    x1 += ks[(i + 2) % 3] + (unsigned)(i + 1);
  }
  o0 = x0; o1 = x1;
}

// JAX threefry_partitionable random_bits: bits[c] = o0^o1 of
// threefry(key=(0,42), counter=(0,c)); uniform = ((bits>>9)|0x3f800000)-1.
__device__ __forceinline__ float col_mask(int c) {
  unsigned o0, o1;
  threefry2x32(0u, (unsigned)c, o0, o1);
  unsigned bits = o0 ^ o1;
  float u = __uint_as_float((bits >> 9) | 0x3f800000u) - 1.0f;
  return (u < 0.75f) ? 1.0f : 0.0f;
}

__device__ __forceinline__ unsigned short f2bf(float f) {
  unsigned u = __float_as_uint(f);
  u += 0x7fffu + ((u >> 16) & 1u);  // round-to-nearest-even
  return (unsigned short)(u >> 16);
}

__device__ __forceinline__ float bflo(unsigned u) {
  return __uint_as_float(u << 16);
}
__device__ __forceinline__ float bfhi(unsigned u) {
  return __uint_as_float(u & 0xffff0000u);
}

__device__ __forceinline__ float rlane(float v, int l) {
  return __int_as_float(__builtin_amdgcn_readlane(__float_as_int(v), l));
}

// ---------------- init: deg=0, dummy row=0, Wt = bf16(W^T) ----------------
// 196 blocks x 256 threads (50176 >= 50000).
__global__ __launch_bounds__(256) void init_kernel(
    const float* __restrict__ W1, const float* __restrict__ W2,
    unsigned short* __restrict__ Wt1, unsigned short* __restrict__ Wt2,
    int* __restrict__ deg, unsigned short* __restrict__ xb) {
  const int gid = blockIdx.x * 256 + threadIdx.x;
  if (gid < N_NODES) deg[gid] = 0;
  if (gid < HIDDEN * HIDDEN / 4) {
#pragma unroll
    for (int i = 0; i < 4; ++i) {
      int t = gid * 4 + i;            // Wt index
      int col = t >> 7, k = t & 127;  // Wt[col][k] = W[k][col]
      Wt1[t] = f2bf(W1[k * HIDDEN + col]);
      Wt2[t] = f2bf(W2[k * HIDDEN + col]);
    }
  }
  if (gid < 16) {
    uint4 z; z.x = 0; z.y = 0; z.z = 0; z.w = 0;
    *reinterpret_cast<uint4*>(xb + (size_t)N_NODES * HIDDEN + gid * 8) = z;
  }
}

// ---------------- prep: hist(dst) + xb = bf16(mask .* x) ----------------
__global__ __launch_bounds__(256) void prep_kernel(
    const float* __restrict__ x, const int* __restrict__ ei,
    unsigned short* __restrict__ xb, int* __restrict__ deg) {
  __shared__ float msk[HIDDEN];
  if (threadIdx.x < HIDDEN) msk[threadIdx.x] = col_mask(threadIdx.x);
  __syncthreads();

  const int gid = blockIdx.x * 256 + threadIdx.x;
  const int e0 = gid * 8;  // 8 contiguous elements
  if (e0 < N_NODES * HIDDEN) {
    const int c0 = e0 & (HIDDEN - 1);
    const float4 v0 = *reinterpret_cast<const float4*>(x + e0);
    const float4 v1 = *reinterpret_cast<const float4*>(x + e0 + 4);
    unsigned short h[8];
    h[0] = f2bf(v0.x * msk[c0 + 0]);
    h[1] = f2bf(v0.y * msk[c0 + 1]);
    h[2] = f2bf(v0.z * msk[c0 + 2]);
    h[3] = f2bf(v0.w * msk[c0 + 3]);
    h[4] = f2bf(v1.x * msk[c0 + 4]);
    h[5] = f2bf(v1.y * msk[c0 + 5]);
    h[6] = f2bf(v1.z * msk[c0 + 6]);
    h[7] = f2bf(v1.w * msk[c0 + 7]);
    *reinterpret_cast<uint4*>(xb + e0) = *reinterpret_cast<uint4*>(h);
  }
  if (gid < N_EDGES) atomicAdd(deg + ei[N_EDGES + gid], 1);
}

// ---------------- two-level scan over PADDED degrees ----------------
__global__ __launch_bounds__(256) void scanA_kernel(const int* __restrict__ deg,
                                                    int* __restrict__ bsum) {
  int idx = blockIdx.x * 256 + threadIdx.x;
  int v = (idx < N_NODES) ? ((deg[idx] + 3) & ~3) : 0;
#pragma unroll
  for (int off = 32; off; off >>= 1) v += __shfl_down(v, off, 64);
  __shared__ int ws4[4];
  if ((threadIdx.x & 63) == 0) ws4[threadIdx.x >> 6] = v;
  __syncthreads();
  if (threadIdx.x == 0) bsum[blockIdx.x] = ws4[0] + ws4[1] + ws4[2] + ws4[3];
}

// Stage C (absorbs old scanB): every block redundantly scans bsum[NB] in LDS
// to get its own prefix, then does the local padded-deg scan + pad writes.
__global__ __launch_bounds__(256) void scanC_kernel(
    const int* __restrict__ deg, const int* __restrict__ bsum,
    int* __restrict__ offs, int* __restrict__ pos,
    unsigned short* __restrict__ csr) {
  __shared__ int sb[256];
  __shared__ int s[256];
  const int t = threadIdx.x;
  const int b = blockIdx.x;

  // inclusive scan of the NB block sums (redundant per block, ~196 ints)
  int bv = (t < NB) ? bsum[t] : 0;
  sb[t] = bv;
  __syncthreads();
  int bacc = bv;
  for (int off = 1; off < 256; off <<= 1) {
    int add = (t >= off) ? sb[t - off] : 0;
    __syncthreads();
    bacc += add;
    sb[t] = bacc;
    __syncthreads();
  }
  const int bpre = (b > 0) ? sb[b - 1] : 0;
  if (b == NB - 1 && t == 0) offs[N_NODES] = sb[NB - 1];

  // local scan of padded degrees
  const int idx = b * 256 + t;
  int d = (idx < N_NODES) ? deg[idx] : 0;
  int v = (d + 3) & ~3;
  s[t] = v;
  __syncthreads();
  int acc = v;
  for (int off = 1; off < 256; off <<= 1) {
    int add = (t >= off) ? s[t - off] : 0;
    __syncthreads();
    acc += add;
    s[t] = acc;
    __syncthreads();
  }
  if (idx < N_NODES) {
    int o = bpre + acc - v;
    offs[idx] = o;
    pos[idx] = o;
    for (int w = o + d; w < o + v; ++w)
      csr[w] = (unsigned short)N_NODES;  // pad -> zero row
  }
}

// 2 edges per thread, vectorized index loads.
__global__ __launch_bounds__(256) void fill_kernel(const int* __restrict__ ei,
                                                   int* __restrict__ pos,
                                                   unsigned short* __restrict__ csr) {
  int e0 = (blockIdx.x * 256 + threadIdx.x) * 2;
  if (e0 >= N_EDGES) return;
  const int2 src2 = *reinterpret_cast<const int2*>(ei + e0);
  const int2 dst2 = *reinterpret_cast<const int2*>(ei + N_EDGES + e0);
  int p0 = atomicAdd(pos + dst2.x, 1);
  csr[p0] = (unsigned short)src2.x;
  int p1 = atomicAdd(pos + dst2.y, 1);
  csr[p1] = (unsigned short)src2.y;
}

// ---------------- gather: quarter-wave rows, depth-2 load pipeline ---------
template <bool LDSIDX>
__device__ __forceinline__ void gather2(
    int base, int wave, int q, int ql, int cs,
    const unsigned short* __restrict__ csr, const unsigned short* scsr,
    const int* loffs, const unsigned short* __restrict__ xb,
    unsigned short* H1) {
#pragma unroll 1
  for (int i = 0; i < 2; ++i) {
    const int row = wave * 8 + i * 4 + q;
    const int node = base + row;
    const bool valid = node < N_NODES;
    const int s = valid ? loffs[row] : 0;
    const int e = valid ? loffs[row + 1] : 0;
    const int on = valid ? node : N_NODES;  // invalid -> zero row
    const uint4 ov =
        *reinterpret_cast<const uint4*>(xb + (size_t)on * HIDDEN + ql * 8);
    float a0 = bflo(ov.x), a1 = bfhi(ov.x);
    float a2 = bflo(ov.y), a3 = bfhi(ov.y);
    float a4 = bflo(ov.z), a5 = bfhi(ov.z);
    float a6 = bflo(ov.w), a7 = bfhi(ov.w);

    const bool h0 = s < e;
    uint2 pk;
    pk.x = 0; pk.y = 0;
    if (h0)
      pk = LDSIDX ? *reinterpret_cast<const uint2*>(scsr + (s - cs))
                  : *reinterpret_cast<const uint2*>(csr + s);
    int i0 = h0 ? (int)(pk.x & 0xffffu) : N_NODES;
    int i1 = h0 ? (int)(pk.x >> 16) : N_NODES;
    int i2 = h0 ? (int)(pk.y & 0xffffu) : N_NODES;
    int i3 = h0 ? (int)(pk.y >> 16) : N_NODES;
    uint4 c0 = *reinterpret_cast<const uint4*>(xb + (size_t)i0 * HIDDEN + ql * 8);
    uint4 c1 = *reinterpret_cast<const uint4*>(xb + (size_t)i1 * HIDDEN + ql * 8);
    uint4 c2 = *reinterpret_cast<const uint4*>(xb + (size_t)i2 * HIDDEN + ql * 8);
    uint4 c3 = *reinterpret_cast<const uint4*>(xb + (size_t)i3 * HIDDEN + ql * 8);

    for (int j = s; j < e; j += 4) {
      const int jn = j + 4;
      const bool more = jn < e;
      uint2 pk2;
      pk2.x = 0; pk2.y = 0;
      if (more)
        pk2 = LDSIDX ? *reinterpret_cast<const uint2*>(scsr + (jn - cs))
                     : *reinterpret_cast<const uint2*>(csr + jn);
      const int n0 = more ? (int)(pk2.x & 0xffffu) : N_NODES;
      const int n1 = more ? (int)(pk2.x >> 16) : N_NODES;
      const int n2 = more ? (int)(pk2.y & 0xffffu) : N_NODES;
      const int n3 = more ? (int)(pk2.y >> 16) : N_NODES;
      const uint4 d0 =
          *reinterpret_cast<const uint4*>(xb + (size_t)n0 * HIDDEN + ql * 8);
      const uint4 d1 =
          *reinterpret_cast<const uint4*>(xb + (size_t)n1 * HIDDEN + ql * 8);
      const uint4 d2 =
          *reinterpret_cast<const uint4*>(xb + (size_t)n2 * HIDDEN + ql * 8);
      const uint4 d3 =
          *reinterpret_cast<const uint4*>(xb + (size_t)n3 * HIDDEN + ql * 8);

      a0 += bflo(c0.x) + bflo(c1.x) + bflo(c2.x) + bflo(c3.x);
      a1 += bfhi(c0.x) + bfhi(c1.x) + bfhi(c2.x) + bfhi(c3.x);
      a2 += bflo(c0.y) + bflo(c1.y) + bflo(c2.y) + bflo(c3.y);
      a3 += bfhi(c0.y) + bfhi(c1.y) + bfhi(c2.y) + bfhi(c3.y);
      a4 += bflo(c0.z) + bflo(c1.z) + bflo(c2.z) + bflo(c3.z);
      a5 += bfhi(c0.z) + bfhi(c1.z) + bfhi(c2.z) + bfhi(c3.z);
      a6 += bflo(c0.w) + bflo(c1.w) + bflo(c2.w) + bflo(c3.w);
      a7 += bfhi(c0.w) + bfhi(c1.w) + bfhi(c2.w) + bfhi(c3.w);

      c0 = d0; c1 = d1; c2 = d2; c3 = d3;
    }
    uint4 pw;
    pw.x = (unsigned)f2bf(a0) | ((unsigned)f2bf(a1) << 16);
    pw.y = (unsigned)f2bf(a2) | ((unsigned)f2bf(a3) << 16);
    pw.z = (unsigned)f2bf(a4) | ((unsigned)f2bf(a5) << 16);
    pw.w = (unsigned)f2bf(a6) | ((unsigned)f2bf(a7) << 16);
    const int byte = (row * 256 + ql * 16) ^ ((row & 7) << 4);
    *reinterpret_cast<uint4*>(reinterpret_cast<char*>(H1) + byte) = pw;
  }
}

// ---------------- fused gather(bf16) + MLP (bf16 MFMA) ----------------
__global__ __launch_bounds__(256) void fused_xb_kernel(
    const int* __restrict__ offs, const unsigned short* __restrict__ csr,
    const unsigned short* __restrict__ xb,
    const unsigned short* __restrict__ Wt1,
    const unsigned short* __restrict__ Wt2, const float* __restrict__ b1,
    const float* __restrict__ b2, float* __restrict__ out) {
  __shared__ unsigned short H1[BR * HIDDEN];              // 8 KB, swizzled
  __shared__ unsigned short H2[BR * HIDDEN];              // 8 KB, swizzled
  __shared__ __align__(16) unsigned short scsr[SCSR_CAP]; // 8 KB staged csr
  __shared__ int loffs[BR + 1];

  const int tid = threadIdx.x;
  const int lane = tid & 63;
  const int wave = tid >> 6;
  const int base = blockIdx.x * BR;

  if (tid < BR + 1) {
    int idx = base + tid;
    loffs[tid] = offs[idx > N_NODES ? N_NODES : idx];
  }
  __syncthreads();
  const int cs = loffs[0];
  const int count = loffs[BR] - cs;
  const bool stage = (count <= SCSR_CAP);
  if (stage) {
    const unsigned* src = reinterpret_cast<const unsigned*>(csr + cs);
    unsigned* dst = reinterpret_cast<unsigned*>(scsr);
    for (int k = tid; k < (count >> 1); k += 256) dst[k] = src[k];
  }
  __syncthreads();

  const int q = lane >> 4;   // quarter index: which row of the 4
  const int ql = lane & 15;  // lane in quarter: cols ql*8 .. ql*8+7

  if (stage)
    gather2<true>(base, wave, q, ql, cs, csr, scsr, loffs, xb, H1);
  else
    gather2<false>(base, wave, q, ql, cs, csr, scsr, loffs, xb, H1);
  __syncthreads();

  // ---- phase 2: GEMM1 (H1 @ Wt1 + b1, relu) -> H2 ----
  const int colbase = wave * 32;  // 2 col-tiles per wave
  float bias1[2], bias2[2];
#pragma unroll
  for (int c = 0; c < 2; ++c) {
    bias1[c] = b1[colbase + c * 16 + (lane & 15)];
    bias2[c] = b2[colbase + c * 16 + (lane & 15)];
  }

  f32x4 acc[2][2] = {};
#pragma unroll
  for (int kt = 0; kt < 4; ++kt) {
    short8v a[2], b[2];
#pragma unroll
    for (int r = 0; r < 2; ++r) {
      int row = r * 16 + (lane & 15);
      int byte = (row * 256 + kt * 64 + (lane >> 4) * 16) ^ ((row & 7) << 4);
      a[r] = *reinterpret_cast<const short8v*>(
          reinterpret_cast<const char*>(H1) + byte);
    }
#pragma unroll
    for (int c = 0; c < 2; ++c) {
      int col = colbase + c * 16 + (lane & 15);
      b[c] = *reinterpret_cast<const short8v*>(
          reinterpret_cast<const char*>(Wt1) + col * 256 + kt * 64 +
          (lane >> 4) * 16);
    }
#pragma unroll
    for (int r = 0; r < 2; ++r)
#pragma unroll
      for (int c = 0; c < 2; ++c)
        acc[r][c] = __builtin_amdgcn_mfma_f32_16x16x32_bf16(a[r], b[c],
                                                            acc[r][c], 0, 0, 0);
  }
#pragma unroll
  for (int r = 0; r < 2; ++r)
#pragma unroll
    for (int c = 0; c < 2; ++c)
#pragma unroll
      for (int q2 = 0; q2 < 4; ++q2) {
        int row = r * 16 + (lane >> 4) * 4 + q2;
        int col = colbase + c * 16 + (lane & 15);
        float v = fmaxf(acc[r][c][q2] + bias1[c], 0.f);
        int byte = (row * 256 + col * 2) ^ ((row & 7) << 4);
        *reinterpret_cast<unsigned short*>(reinterpret_cast<char*>(H2) + byte) =
            f2bf(v);
      }
  __syncthreads();

  // ---- phase 3: GEMM2 (H2 @ Wt2 + b2) -> out ----
  f32x4 acc2[2][2] = {};
#pragma unroll
  for (int kt = 0; kt < 4; ++kt) {
    short8v a[2], b[2];
#pragma unroll
    for (int r = 0; r < 2; ++r) {
      int row = r * 16 + (lane & 15);
      int byte = (row * 256 + kt * 64 + (lane >> 4) * 16) ^ ((row & 7) << 4);
      a[r] = *reinterpret_cast<const short8v*>(
          reinterpret_cast<const char*>(H2) + byte);
    }
#pragma unroll
    for (int c = 0; c < 2; ++c) {
      int col = colbase + c * 16 + (lane & 15);
      b[c] = *reinterpret_cast<const short8v*>(
          reinterpret_cast<const char*>(Wt2) + col * 256 + kt * 64 +
          (lane >> 4) * 16);
    }
#pragma unroll
    for (int r = 0; r < 2; ++r)
#pragma unroll
      for (int c = 0; c < 2; ++c)
        acc2[r][c] = __builtin_amdgcn_mfma_f32_16x16x32_bf16(
            a[r], b[c], acc2[r][c], 0, 0, 0);
  }
#pragma unroll
  for (int r = 0; r < 2; ++r)
#pragma unroll
    for (int c = 0; c < 2; ++c)
#pragma unroll
      for (int q2 = 0; q2 < 4; ++q2) {
        int row = base + r * 16 + (lane >> 4) * 4 + q2;
        if (row < N_NODES) {
          int col = colbase + c * 16 + (lane & 15);
          out[(size_t)row * HIDDEN + col] = acc2[r][c][q2] + bias2[c];
        }
      }
}

// ---------------- Tier-C fallback (round-2 proven) ----------------
__global__ __launch_bounds__(256) void scatter_kernel(
    const int* __restrict__ ei, const float* __restrict__ x,
    float* __restrict__ agg) {
  long long gid = (long long)blockIdx.x * blockDim.x + threadIdx.x;
  int e = (int)(gid >> 5);
  if (e >= N_EDGES) return;
  int sub = ((int)gid & 31) * 4;
  int src = ei[e];
  int dst = ei[N_EDGES + e];
  const float4 v = *reinterpret_cast<const float4*>(x + src * HIDDEN + sub);
  float* p = agg + dst * HIDDEN + sub;
  atomicAdd(p + 0, v.x);
  atomicAdd(p + 1, v.y);
  atomicAdd(p + 2, v.z);
  atomicAdd(p + 3, v.w);
}

__global__ __launch_bounds__(512) void mlp_kernel(
    const float* __restrict__ x, float* __restrict__ io,
    const float* __restrict__ W1, const float* __restrict__ b1,
    const float* __restrict__ W2, const float* __restrict__ b2) {
  __shared__ float W1s[HIDDEN * HIDDEN];
  __shared__ float W2s[HIDDEN * HIDDEN];

  const int tid = threadIdx.x;
#pragma unroll
  for (int i = 0; i < 8; ++i) {
    int idx = (i * 512 + tid) * 4;
    *reinterpret_cast<float4*>(W1s + idx) =
        *reinterpret_cast<const float4*>(W1 + idx);
    *reinterpret_cast<float4*>(W2s + idx) =
        *reinterpret_cast<const float4*>(W2 + idx);
  }

  const int lane = tid & 63;
  const int wave = tid >> 6;
  const int c0 = 2 * lane, c1 = 2 * lane + 1;

  const float m0 = col_mask(c0);
  const float m1 = col_mask(c1);
  const float bb1x = b1[c0], bb1y = b1[c1];
  const float bb2x = b2[c0], bb2y = b2[c1];

  __syncthreads();

  const int gwave = blockIdx.x * 8 + wave;
  const int nwaves = gridDim.x * 8;

  for (int pr = gwave; pr < N_NODES / 2; pr += nwaves) {
    const int baseA = (2 * pr) * HIDDEN;
    const int baseB = baseA + HIDDEN;

    float2 xA = *reinterpret_cast<const float2*>(x + baseA + c0);
    float2 gA = *reinterpret_cast<const float2*>(io + baseA + c0);
    float2 xB = *reinterpret_cast<const float2*>(x + baseB + c0);
    float2 gB = *reinterpret_cast<const float2*>(io + baseB + c0);

    float hA0 = m0 * (xA.x + gA.x), hA1 = m1 * (xA.y + gA.y);
    float hB0 = m0 * (xB.x + gB.x), hB1 = m1 * (xB.y + gB.y);

    float aA0 = bb1x, aA1 = bb1y, aB0 = bb1x, aB1 = bb1y;
#pragma unroll
    for (int k = 0; k < HIDDEN; ++k) {
      const int sl = k >> 1;
      float hkA = (k & 1) ? rlane(hA1, sl) : rlane(hA0, sl);
      float hkB = (k & 1) ? rlane(hB1, sl) : rlane(hB0, sl);
      float2 w = *reinterpret_cast<const float2*>(W1s + k * HIDDEN + c0);
      aA0 = fmaf(hkA, w.x, aA0);
      aA1 = fmaf(hkA, w.y, aA1);
      aB0 = fmaf(hkB, w.x, aB0);
      aB1 = fmaf(hkB, w.y, aB1);
    }
    aA0 = fmaxf(aA0, 0.0f); aA1 = fmaxf(aA1, 0.0f);
    aB0 = fmaxf(aB0, 0.0f); aB1 = fmaxf(aB1, 0.0f);

    float oA0 = bb2x, oA1 = bb2y, oB0 = bb2x, oB1 = bb2y;
#pragma unroll
    for (int k = 0; k < HIDDEN; ++k) {
      const int sl = k >> 1;
      float hkA = (k & 1) ? rlane(aA1, sl) : rlane(aA0, sl);
      float hkB = (k & 1) ? rlane(aB1, sl) : rlane(aB0, sl);
      float2 w = *reinterpret_cast<const float2*>(W2s + k * HIDDEN + c0);
      oA0 = fmaf(hkA, w.x, oA0);
      oA1 = fmaf(hkA, w.y, oA1);
      oB0 = fmaf(hkB, w.x, oB0);
      oB1 = fmaf(hkB, w.y, oB1);
    }

    *reinterpret_cast<float2*>(io + baseA + c0) = make_float2(oA0, oA1);
    *reinterpret_cast<float2*>(io + baseB + c0) = make_float2(oB0, oB1);
  }
}

extern "C" void kernel_launch(void* const* d_in, const int* in_sizes, int n_in,
                              void* d_out, int out_size, void* d_ws,
                              size_t ws_size, hipStream_t stream) {
  (void)in_sizes; (void)n_in; (void)out_size;
  const float* x  = (const float*)d_in[0];
  const int*   ei = (const int*)d_in[1];
  const float* W1 = (const float*)d_in[2];
  const float* b1 = (const float*)d_in[3];
  const float* W2 = (const float*)d_in[4];
  const float* b2 = (const float*)d_in[5];
  float* out = (float*)d_out;

  // ws layout: [ints: deg N | offs N+1 | pos N | bsum NB] pad16
  //            [u16: csr E_PAD_MAX] [u16: Wt1 16384 | Wt2 16384]
  //            [u16: xb (N_NODES+1)*HIDDEN]
  const size_t int_words = (size_t)N_NODES + (N_NODES + 1) + N_NODES + NB;
  const size_t int_pad   = (int_words * 4 + 15) & ~(size_t)15;
  const size_t csr_bytes = (size_t)E_PAD_MAX * 2;
  const size_t wt_bytes  = 2 * (size_t)HIDDEN * HIDDEN * 2;
  const size_t xb_bytes  = (size_t)(N_NODES + 1) * HIDDEN * 2;
  const size_t need = int_pad + csr_bytes + wt_bytes + xb_bytes;

  if (ws_size >= need) {
    char* wsb = (char*)d_ws;
    int* deg  = (int*)wsb;
    int* offs = deg + N_NODES;
    int* pos  = offs + N_NODES + 1;
    int* bsum = pos + N_NODES;
    unsigned short* csr = (unsigned short*)(wsb + int_pad);
    unsigned short* Wt1 = (unsigned short*)(wsb + int_pad + csr_bytes);
    unsigned short* Wt2 = Wt1 + HIDDEN * HIDDEN;
    unsigned short* xb  = Wt2 + HIDDEN * HIDDEN;

    init_kernel<<<NB, 256, 0, stream>>>(W1, W2, Wt1, Wt2, deg, xb);
    const int nprep = (N_NODES * HIDDEN / 8 + 255) / 256;  // 3125
    prep_kernel<<<nprep, 256, 0, stream>>>(x, ei, xb, deg);
    scanA_kernel<<<NB, 256, 0, stream>>>(deg, bsum);
    scanC_kernel<<<NB, 256, 0, stream>>>(deg, bsum, offs, pos, csr);
    fill_kernel<<<(N_EDGES / 2 + 255) / 256, 256, 0, stream>>>(ei, pos, csr);
    fused_xb_kernel<<<NTILES, 256, 0, stream>>>(offs, csr, xb, Wt1, Wt2, b1,
                                                b2, out);
  } else {
    // Tier C: atomic scatter + rlane MLP (proven, slow).
    hipMemsetAsync(out, 0, (size_t)N_NODES * HIDDEN * sizeof(float), stream);
    const long long total = (long long)N_EDGES * 32;
    scatter_kernel<<<(int)((total + 255) / 256), 256, 0, stream>>>(ei, x, out);
    mlp_kernel<<<256, 512, 0, stream>>>(x, out, W1, b1, W2, b2);
  }
}